// Round 1
// baseline (681.860 us; speedup 1.0000x reference)
//
#include <hip/hip_runtime.h>

#define DIM 1024
#define NROWS 65536
#define PICK 12

// -------------------------------------------------------------------------
// ws layout (floats):
//   0      NK  [12][1024]
//   12288  Qr  [12][1024]
//   24576  M   [1024][12]   (zeroed, atomic-accumulated)
//   36864  Rt  [1024][12]   (zeroed, atomic-accumulated)
//   49152  c0  [12] (pad16, zeroed)
//   49168  c1  [12] (pad16, zeroed)
//   49184  cand_v [3072]
//   52256  cand_i [3072] (int)
//   55328  top_idx [12] (int, pad16)
//   55344  maxv [65536]
//   total 120880 floats = 483,520 B
// -------------------------------------------------------------------------

// out[j][d] = sum_e emb[idx[j]][e] * W[d][e] + b[d]      (12 x 1024)
// grid 1024 (one block per d), block 256
__global__ void __launch_bounds__(256)
rows12_kernel(const float* __restrict__ emb, const float* __restrict__ W,
              const float* __restrict__ b, const int* __restrict__ idx,
              float* __restrict__ out) {
    int d = blockIdx.x;
    int t = threadIdx.x;
    int lane = t & 63;
    int q = t >> 6;                 // wave id: e-quarter
    int e0 = q * 256 + lane * 4;
    float4 w4 = *(const float4*)&W[(size_t)d * DIM + e0];
    float part[PICK];
#pragma unroll
    for (int j = 0; j < PICK; ++j) {
        int r = idx[j];
        float4 e4 = *(const float4*)&emb[(size_t)r * DIM + e0];
        part[j] = w4.x * e4.x + w4.y * e4.y + w4.z * e4.z + w4.w * e4.w;
    }
#pragma unroll
    for (int j = 0; j < PICK; ++j) {
        float v = part[j];
        for (int s = 32; s > 0; s >>= 1) v += __shfl_down(v, s, 64);
        part[j] = v;
    }
    __shared__ float red[4][PICK];
    if (lane == 0) {
#pragma unroll
        for (int j = 0; j < PICK; ++j) red[q][j] = part[j];
    }
    __syncthreads();
    if (t < PICK) {
        float s = red[0][t] + red[1][t] + red[2][t] + red[3][t] + b[d];
        out[t * DIM + d] = s;
    }
}

// out[e][j] += sum_d W[d][e] * V[j][d]   and  cvec[j] += sum_d b[d]*V[j][d]
// grid 33 (32 = 4 e-groups x 8 d-groups, block 32 = cvec), block 256
__global__ void __launch_bounds__(256)
colmat_kernel(const float* __restrict__ W, const float* __restrict__ V,
              const float* __restrict__ b, float* __restrict__ out,
              float* __restrict__ cvec) {
    int blk = blockIdx.x;
    int t = threadIdx.x;
    if (blk == 32) {
        float part[PICK];
#pragma unroll
        for (int j = 0; j < PICK; ++j) part[j] = 0.f;
        for (int k = 0; k < 4; ++k) {
            int d = t + k * 256;
            float bv = b[d];
#pragma unroll
            for (int j = 0; j < PICK; ++j) part[j] += bv * V[j * DIM + d];
        }
#pragma unroll
        for (int j = 0; j < PICK; ++j) {
            float v = part[j];
            for (int s = 32; s > 0; s >>= 1) v += __shfl_down(v, s, 64);
            if ((t & 63) == 0) atomicAdd(&cvec[j], v);
        }
        return;
    }
    int eg = blk & 3;
    int dg = blk >> 2;
    int e = eg * 256 + t;
    int d0 = dg * 128;
    __shared__ float Vs[PICK][128];
    for (int i = t; i < PICK * 128; i += 256) {
        int j = i >> 7, dd = i & 127;
        Vs[j][dd] = V[j * DIM + d0 + dd];
    }
    __syncthreads();
    float acc[PICK];
#pragma unroll
    for (int j = 0; j < PICK; ++j) acc[j] = 0.f;
    for (int dd = 0; dd < 128; ++dd) {
        float w = W[(size_t)(d0 + dd) * DIM + e];
#pragma unroll
        for (int j = 0; j < PICK; ++j) acc[j] += w * Vs[j][dd];
    }
#pragma unroll
    for (int j = 0; j < PICK; ++j) atomicAdd(&out[e * PICK + j], acc[j]);
}

// maxv[n] = max_j ( sum_e emb[n][e]*M[e][j] + c0[j] )
// grid 1024 (64 rows/block), block 256: lane = row, wave = e-quarter
__global__ void __launch_bounds__(256)
pass1_kernel(const float* __restrict__ emb, const float* __restrict__ M,
             const float* __restrict__ c0, float* __restrict__ maxv) {
    int t = threadIdx.x;
    int lane = t & 63;
    int q = __builtin_amdgcn_readfirstlane(t >> 6);   // wave-uniform
    int row = blockIdx.x * 64 + lane;
    const float* erow = emb + (size_t)row * DIM + q * 256;
    const float* Mq = M + (size_t)q * 256 * PICK;
    float acc[PICK];
#pragma unroll
    for (int j = 0; j < PICK; ++j) acc[j] = 0.f;
    for (int e = 0; e < 256; e += 4) {
        float4 v = *(const float4*)(erow + e);
        const float* m = Mq + e * PICK;
#pragma unroll
        for (int j = 0; j < PICK; ++j)
            acc[j] += v.x * m[j] + v.y * m[j + 12] + v.z * m[j + 24] + v.w * m[j + 36];
    }
    __shared__ float red[4][64][PICK + 1];
#pragma unroll
    for (int j = 0; j < PICK; ++j) red[q][lane][j] = acc[j];
    __syncthreads();
    if (t < 64) {
        float mx = -3e38f;
#pragma unroll
        for (int j = 0; j < PICK; ++j) {
            float s = red[0][t][j] + red[1][t][j] + red[2][t][j] + red[3][t][j] + c0[j];
            mx = fmaxf(mx, s);
        }
        maxv[blockIdx.x * 64 + t] = mx;
    }
}

// pooled[n] = max_j ( sum_e emb[n][e]*Rt[e][j] + c1[j] ); out[d] += sum pooled*emb
__global__ void __launch_bounds__(256)
pass2_kernel(const float* __restrict__ emb, const float* __restrict__ Rt,
             const float* __restrict__ c1, float* __restrict__ out) {
    int t = threadIdx.x;
    int lane = t & 63;
    int q = __builtin_amdgcn_readfirstlane(t >> 6);
    int row = blockIdx.x * 64 + lane;
    const float* erow = emb + (size_t)row * DIM + q * 256;
    const float* Mq = Rt + (size_t)q * 256 * PICK;
    float acc[PICK];
#pragma unroll
    for (int j = 0; j < PICK; ++j) acc[j] = 0.f;
    for (int e = 0; e < 256; e += 4) {
        float4 v = *(const float4*)(erow + e);
        const float* m = Mq + e * PICK;
#pragma unroll
        for (int j = 0; j < PICK; ++j)
            acc[j] += v.x * m[j] + v.y * m[j + 12] + v.z * m[j + 24] + v.w * m[j + 36];
    }
    __shared__ float red[4][64][PICK + 1];
    __shared__ float pool[64];
#pragma unroll
    for (int j = 0; j < PICK; ++j) red[q][lane][j] = acc[j];
    __syncthreads();
    if (t < 64) {
        float mx = -3e38f;
#pragma unroll
        for (int j = 0; j < PICK; ++j) {
            float s = red[0][t][j] + red[1][t][j] + red[2][t][j] + red[3][t][j] + c1[j];
            mx = fmaxf(mx, s);
        }
        pool[t] = mx;
    }
    __syncthreads();
    // out[d] += sum_r pool[r] * emb[n0+r][d], thread t owns d = 4t..4t+3
    const float* ep = emb + (size_t)blockIdx.x * 64 * DIM + t * 4;
    float ax = 0.f, ay = 0.f, az = 0.f, aw = 0.f;
    for (int r = 0; r < 64; ++r) {
        float p = pool[r];
        float4 v = *(const float4*)(ep + (size_t)r * DIM);
        ax += p * v.x; ay += p * v.y; az += p * v.z; aw += p * v.w;
    }
    atomicAdd(&out[t * 4 + 0], ax);
    atomicAdd(&out[t * 4 + 1], ay);
    atomicAdd(&out[t * 4 + 2], az);
    atomicAdd(&out[t * 4 + 3], aw);
}

// local top-12 of each 256-chunk of maxv -> 256 blocks x 12 candidates
__global__ void __launch_bounds__(256)
top12_local(const float* __restrict__ maxv, float* __restrict__ cand_v,
            int* __restrict__ cand_i) {
    int t = threadIdx.x;
    int base = blockIdx.x * 256;
    __shared__ float mv[256];
    __shared__ float sv[256];
    __shared__ int si[256];
    mv[t] = maxv[base + t];
    __syncthreads();
    for (int k = 0; k < PICK; ++k) {
        sv[t] = mv[t]; si[t] = t;
        __syncthreads();
        for (int s = 128; s > 0; s >>= 1) {
            if (t < s) {
                if (sv[t + s] > sv[t] || (sv[t + s] == sv[t] && si[t + s] < si[t])) {
                    sv[t] = sv[t + s]; si[t] = si[t + s];
                }
            }
            __syncthreads();
        }
        if (t == 0) {
            cand_v[blockIdx.x * PICK + k] = sv[0];
            cand_i[blockIdx.x * PICK + k] = base + si[0];
            mv[si[0]] = -3e38f;
        }
        __syncthreads();
    }
}

// merge 3072 candidates -> global top-12 indices
__global__ void __launch_bounds__(256)
top12_merge(const float* __restrict__ cand_v, const int* __restrict__ cand_i,
            int* __restrict__ top_idx) {
    int t = threadIdx.x;
    __shared__ float mv[3072];
    __shared__ int mi[3072];
    __shared__ float sv[256];
    __shared__ int si[256];
    __shared__ int sl[256];
    for (int i = t; i < 3072; i += 256) { mv[i] = cand_v[i]; mi[i] = cand_i[i]; }
    __syncthreads();
    for (int k = 0; k < PICK; ++k) {
        float bv = -3e38f; int bi = 0x7fffffff; int bl = -1;
        for (int i = t; i < 3072; i += 256) {
            float v = mv[i]; int ii = mi[i];
            if (v > bv || (v == bv && ii < bi)) { bv = v; bi = ii; bl = i; }
        }
        sv[t] = bv; si[t] = bi; sl[t] = bl;
        __syncthreads();
        for (int s = 128; s > 0; s >>= 1) {
            if (t < s) {
                if (sv[t + s] > sv[t] || (sv[t + s] == sv[t] && si[t + s] < si[t])) {
                    sv[t] = sv[t + s]; si[t] = si[t + s]; sl[t] = sl[t + s];
                }
            }
            __syncthreads();
        }
        if (t == 0) { top_idx[k] = si[0]; mv[sl[0]] = -3e38f; }
        __syncthreads();
    }
}

extern "C" void kernel_launch(void* const* d_in, const int* in_sizes, int n_in,
                              void* d_out, int out_size, void* d_ws, size_t ws_size,
                              hipStream_t stream) {
    const float* emb = (const float*)d_in[0];
    const float* Wq  = (const float*)d_in[1];
    const float* bq  = (const float*)d_in[2];
    const float* Wk  = (const float*)d_in[3];
    const float* bk  = (const float*)d_in[4];
    const int* indices = (const int*)d_in[5];
    float* out = (float*)d_out;
    float* ws = (float*)d_ws;

    float* NK      = ws;             // 12288
    float* Qr      = ws + 12288;     // 12288
    float* M       = ws + 24576;     // 12288 (zeroed)
    float* Rt      = ws + 36864;     // 12288 (zeroed)
    float* c0      = ws + 49152;     // 16    (zeroed)
    float* c1      = ws + 49168;     // 16    (zeroed)
    float* cand_v  = ws + 49184;     // 3072
    int*   cand_i  = (int*)(ws + 52256);   // 3072
    int*   top_idx = (int*)(ws + 55328);   // 16
    float* maxv    = ws + 55344;     // 65536

    // zero the atomic-accumulated regions (M, Rt, c0, c1) and the output
    hipMemsetAsync(M, 0, (size_t)(12288 * 2 + 32) * sizeof(float), stream);
    hipMemsetAsync(out, 0, DIM * sizeof(float), stream);

    rows12_kernel<<<1024, 256, 0, stream>>>(emb, Wk, bk, indices, NK);
    colmat_kernel<<<33, 256, 0, stream>>>(Wq, NK, bq, M, c0);
    pass1_kernel<<<1024, 256, 0, stream>>>(emb, M, c0, maxv);
    top12_local<<<256, 256, 0, stream>>>(maxv, cand_v, cand_i);
    top12_merge<<<1, 256, 0, stream>>>(cand_v, cand_i, top_idx);
    rows12_kernel<<<1024, 256, 0, stream>>>(emb, Wq, bq, top_idx, Qr);
    colmat_kernel<<<33, 256, 0, stream>>>(Wk, Qr, bk, Rt, c1);
    pass2_kernel<<<1024, 256, 0, stream>>>(emb, Rt, c1, out);
}